// Round 3
// baseline (873.889 us; speedup 1.0000x reference)
//
#include <hip/hip_runtime.h>
#include <hip/hip_bf16.h>
#include <cstdint>
#include <cstddef>

#define N_TOK 8192
#define DIM   2048
#define HID   2048
#define NE    8

typedef _Float16 half8  __attribute__((ext_vector_type(8)));
typedef _Float16 half4v __attribute__((ext_vector_type(4)));
typedef float    floatx4 __attribute__((ext_vector_type(4)));

__device__ inline void gload_lds16(const void* g, void* l) {
    __builtin_amdgcn_global_load_lds(
        (const __attribute__((address_space(1))) unsigned int*)g,
        (__attribute__((address_space(3))) unsigned int*)l, 16, 0, 0);
}

// ---------------- fused W1+W2 [E][R][C] fp32 -> [E][C][R] fp16 ----------------
__global__ __launch_bounds__(256) void k_prep(const float* __restrict__ W1,
                                              const float* __restrict__ W2,
                                              _Float16* __restrict__ w1t,
                                              _Float16* __restrict__ w2t) {
    __shared__ float tile[64][65];
    int z = blockIdx.z;
    const float* in = (z < 8) ? W1 : W2;
    _Float16* out   = (z < 8) ? w1t : w2t;
    int e  = z & 7;
    int r0 = blockIdx.y * 64;
    int c0 = blockIdx.x * 64;
    int tc = threadIdx.x & 63, tr = threadIdx.x >> 6; // tr 0..3
    const float* ip = in + ((size_t)e * 2048 + r0) * 2048 + c0;
#pragma unroll
    for (int i = 0; i < 16; i++)
        tile[tr + i * 4][tc] = ip[(size_t)(tr + i * 4) * 2048 + tc];
    __syncthreads();
    _Float16* op = out + ((size_t)e * 2048 + c0) * 2048 + r0;
#pragma unroll
    for (int i = 0; i < 16; i++) {
        int cc = tr + i * 4;
        op[(size_t)cc * 2048 + tc] = (_Float16)tile[tc][cc];
    }
}

// ---------------- gate: logits (fp64 accum), top-2, softmax; fuses x->fp16 ----------------
__global__ __launch_bounds__(256) void k_gate(const float* __restrict__ x,
                                              const float* __restrict__ Wg,
                                              const float* __restrict__ bg,
                                              _Float16* __restrict__ xh,
                                              int* __restrict__ te, float* __restrict__ tw,
                                              int* __restrict__ counts) {
    __shared__ float wgs[NE * DIM]; // 64 KB, transposed [e][d]
    for (int i = threadIdx.x; i < NE * DIM; i += 256) {
        float v = Wg[i];                       // Wg[d][e]: d=i>>3, e=i&7
        wgs[(i & 7) * DIM + (i >> 3)] = v;
    }
    __syncthreads();
    int wv = threadIdx.x >> 6, l = threadIdx.x & 63;
#pragma unroll 1
    for (int it = 0; it < 8; ++it) {
        int t = blockIdx.x * 32 + wv * 8 + it;
        const float* xr = x + (size_t)t * DIM;
        double acc[NE] = {0, 0, 0, 0, 0, 0, 0, 0};
#pragma unroll
        for (int i = 0; i < 8; i++) {
            int d0 = i * 256 + l * 4;
            float4 xv = *(const float4*)(xr + d0);
            half4v hv;
            hv[0] = (_Float16)xv.x; hv[1] = (_Float16)xv.y;
            hv[2] = (_Float16)xv.z; hv[3] = (_Float16)xv.w;
            *(half4v*)(xh + (size_t)t * DIM + d0) = hv;
#pragma unroll
            for (int e = 0; e < NE; e++) {
                float4 w4 = *(const float4*)(wgs + e * DIM + d0);
                acc[e] += (double)xv.x * w4.x + (double)xv.y * w4.y +
                          (double)xv.z * w4.z + (double)xv.w * w4.w;
            }
        }
#pragma unroll
        for (int e = 0; e < NE; e++) {
            double v = acc[e];
            v += __shfl_xor(v, 32, 64); v += __shfl_xor(v, 16, 64);
            v += __shfl_xor(v, 8, 64);  v += __shfl_xor(v, 4, 64);
            v += __shfl_xor(v, 2, 64);  v += __shfl_xor(v, 1, 64);
            acc[e] = v;
        }
        if (l == 0) {
            double best0 = -1e300, best1 = -1e300; int i0 = 0, i1 = 0;
#pragma unroll
            for (int e = 0; e < NE; e++) {
                double lg = acc[e] + (double)bg[e];
                if (lg > best0) { best1 = best0; i1 = i0; best0 = lg; i0 = e; }
                else if (lg > best1) { best1 = lg; i1 = e; }
            }
            float d  = expf((float)(best1 - best0));
            float w0 = 1.f / (1.f + d), w1 = d / (1.f + d);
            te[2 * t] = i0; te[2 * t + 1] = i1;
            tw[2 * t] = w0; tw[2 * t + 1] = w1;
            atomicAdd(&counts[i0], 1);
            atomicAdd(&counts[i1], 1);
        }
    }
}

// ---------------- tiny scan ----------------
__global__ void k_scan(const int* __restrict__ counts, int* __restrict__ offs,
                       int* __restrict__ fill) {
    if (threadIdx.x == 0 && blockIdx.x == 0) {
        int s = 0;
        for (int e = 0; e < NE; e++) { offs[e] = s; s += counts[e]; fill[e] = 0; }
        offs[NE] = s;
    }
}

// ---------------- scatter tokens to expert lists ----------------
__global__ __launch_bounds__(256) void k_scatter(const int* __restrict__ te,
                                                 const float* __restrict__ tw,
                                                 const int* __restrict__ offs,
                                                 int* __restrict__ fill,
                                                 int* __restrict__ ltok,
                                                 float* __restrict__ lw,
                                                 int* __restrict__ tslot) {
    int t = blockIdx.x * blockDim.x + threadIdx.x;
    if (t >= N_TOK) return;
#pragma unroll
    for (int k = 0; k < 2; k++) {
        int e = te[2 * t + k];
        int p = atomicAdd(&fill[e], 1);
        int idx = offs[e] + p;
        ltok[idx] = t; lw[idx] = tw[2 * t + k]; tslot[2 * t + k] = idx;
    }
}

// ================= m97-structure GEMM (BM=BN=128, BK=64) + XOR swizzle =================
// 256 threads = 4 waves (2m x 2n), wave tile 64x64 = 4x4 frags of 16x16.
// LDS 32 KB single-buffered -> ~4-5 resident blocks/CU mask the sync stalls (m114).
// Swizzle (both-sides, rule 21): logical 16B chunk c of row r lives at physical
// chunk c ^ (r&7). Staged via pre-swizzled GLOBAL source column + linear LDS dest.
template<int LAYER>
__global__ __launch_bounds__(256) void k_gemm(const _Float16* __restrict__ Ain,
                                              const _Float16* __restrict__ Bt,
                                              const float* __restrict__ bias,
                                              const int* __restrict__ counts,
                                              const int* __restrict__ offs,
                                              const int* __restrict__ ltok,
                                              const float* __restrict__ lw,
                                              _Float16* __restrict__ Cout) {
    int e = blockIdx.z;
    int cnt = counts[e];
    int m0 = blockIdx.y * 128;
    if (m0 >= cnt) return;
    int n0 = blockIdx.x * 128;
    int base = offs[e];

    __shared__ _Float16 As[128 * 64];
    __shared__ _Float16 Bs[128 * 64];

    int tid = threadIdx.x;
    int l = tid & 63;
    int wid = tid >> 6;
    int wm = wid >> 1, wn = wid & 1;

    // staging: thread covers LDS row srow (+i*32), physical chunk tid&7;
    // global source column chunk pre-swizzled so physical holds logical^(row&7).
    int srow = tid >> 3;                                  // 0..31
    size_t koff = (size_t)(((tid & 7) ^ (srow & 7)) * 8); // fp16 elems
    const _Float16* aPtr[4];
    const _Float16* bPtr[4];
#pragma unroll
    for (int i = 0; i < 4; i++) {
        int r = m0 + srow + i * 32; if (r > cnt - 1) r = cnt - 1;
        if constexpr (LAYER == 1) {
            int tok = ltok[base + r];
            aPtr[i] = Ain + (size_t)tok * DIM + koff;
        } else {
            aPtr[i] = Ain + (size_t)(base + r) * HID + koff;
        }
        bPtr[i] = Bt + ((size_t)e * 2048 + n0 + srow + i * 32) * 2048 + koff;
    }

    floatx4 acc[4][4];
#pragma unroll
    for (int m = 0; m < 4; m++)
#pragma unroll
        for (int n = 0; n < 4; n++) acc[m][n] = (floatx4){0.f, 0.f, 0.f, 0.f};

    int lr = l & 15, lk = l >> 4, sw = l & 7;
    int cbo0 = ((lk) ^ sw) * 8;       // kk=0: logical chunk lk
    int cbo1 = ((4 + lk) ^ sw) * 8;   // kk=1: logical chunk 4+lk

    for (int kt = 0; kt < DIM / 64; ++kt) {
#pragma unroll
        for (int i = 0; i < 4; i++) gload_lds16(aPtr[i] + (size_t)kt * 64, &As[tid * 8 + i * 2048]);
#pragma unroll
        for (int i = 0; i < 4; i++) gload_lds16(bPtr[i] + (size_t)kt * 64, &Bs[tid * 8 + i * 2048]);
        __syncthreads();
#pragma unroll
        for (int kk = 0; kk < 2; kk++) {
            int cbo = kk ? cbo1 : cbo0;
            half8 af[4], bf[4];
#pragma unroll
            for (int m = 0; m < 4; m++)
                af[m] = *(const half8*)&As[(wm * 64 + m * 16 + lr) * 64 + cbo];
#pragma unroll
            for (int n = 0; n < 4; n++)
                bf[n] = *(const half8*)&Bs[(wn * 64 + n * 16 + lr) * 64 + cbo];
#pragma unroll
            for (int m = 0; m < 4; m++)
#pragma unroll
                for (int n = 0; n < 4; n++)
                    acc[m][n] = __builtin_amdgcn_mfma_f32_16x16x32_f16(af[m], bf[n], acc[m][n], 0, 0, 0);
        }
        __syncthreads();
    }

    int rbase = lk * 4;
#pragma unroll
    for (int n = 0; n < 4; n++) {
        int col = n0 + wn * 64 + n * 16 + lr;
        float bv = bias[e * 2048 + col];
#pragma unroll
        for (int m = 0; m < 4; m++) {
            int row0 = m0 + wm * 64 + m * 16 + rbase;
#pragma unroll
            for (int r = 0; r < 4; r++) {
                int row = row0 + r;
                if (row < cnt) {
                    float v = acc[m][n][r] + bv;
                    if constexpr (LAYER == 1) {
                        v = v > 0.f ? v : 0.f;
                    } else {
                        v *= lw[base + row];
                    }
                    Cout[(size_t)(base + row) * HID + col] = (_Float16)v;
                }
            }
        }
    }
}

// ---------------- combine the two weighted expert rows per token ----------------
__global__ __launch_bounds__(256) void k_combine(const _Float16* __restrict__ yb,
                                                 const int* __restrict__ tslot,
                                                 float* __restrict__ out) {
    int t = blockIdx.x;
    int s0 = tslot[2 * t], s1 = tslot[2 * t + 1];
    int c = threadIdx.x * 8;
    half8 y0 = *(const half8*)&yb[(size_t)s0 * HID + c];
    half8 y1 = *(const half8*)&yb[(size_t)s1 * HID + c];
    float* op = out + (size_t)t * HID + c;
    float4 o;
    o.x = (float)y0[0] + (float)y1[0];
    o.y = (float)y0[1] + (float)y1[1];
    o.z = (float)y0[2] + (float)y1[2];
    o.w = (float)y0[3] + (float)y1[3];
    *(float4*)(op) = o;
    o.x = (float)y0[4] + (float)y1[4];
    o.y = (float)y0[5] + (float)y1[5];
    o.z = (float)y0[6] + (float)y1[6];
    o.w = (float)y0[7] + (float)y1[7];
    *(float4*)(op + 4) = o;
}

extern "C" void kernel_launch(void* const* d_in, const int* in_sizes, int n_in,
                              void* d_out, int out_size, void* d_ws, size_t ws_size,
                              hipStream_t stream) {
    const float* x  = (const float*)d_in[0];
    const float* Wg = (const float*)d_in[1];
    const float* bg = (const float*)d_in[2];
    const float* W1 = (const float*)d_in[3];
    const float* b1 = (const float*)d_in[4];
    const float* W2 = (const float*)d_in[5];
    const float* b2 = (const float*)d_in[6];
    float* out = (float*)d_out;

    char* ws = (char*)d_ws;
    _Float16* xh  = (_Float16*)(ws);                       // 33,554,432 B
    _Float16* w1t = (_Float16*)(ws + 33554432ULL);         // 67,108,864 B
    _Float16* w2t = (_Float16*)(ws + 100663296ULL);        // 67,108,864 B
    _Float16* hb  = (_Float16*)(ws + 167772160ULL);        // 67,108,864 B
    _Float16* yb  = (_Float16*)(ws + 234881024ULL);        // 67,108,864 B
    char* rt = ws + 301989888ULL;
    int*   counts = (int*)(rt);             // 8 ints
    int*   fill   = (int*)(rt + 32);        // 8 ints
    int*   offs   = (int*)(rt + 64);        // 9 ints
    int*   te     = (int*)(rt + 128);
    float* tw     = (float*)(rt + 128 + 65536);
    int*   ltok   = (int*)(rt + 128 + 131072);
    float* lw     = (float*)(rt + 128 + 196608);
    int*   tslot  = (int*)(rt + 128 + 262144);

    hipMemsetAsync(rt, 0, 64, stream);  // counts + fill
    k_prep<<<dim3(32, 32, 16), 256, 0, stream>>>(W1, W2, w1t, w2t);
    k_gate<<<256, 256, 0, stream>>>(x, Wg, bg, xh, te, tw, counts);
    k_scan<<<1, 64, 0, stream>>>(counts, offs, fill);
    k_scatter<<<32, 256, 0, stream>>>(te, tw, offs, fill, ltok, lw, tslot);
    k_gemm<1><<<dim3(16, 24, 8), 256, 0, stream>>>(xh, w1t, b1, counts, offs, ltok, nullptr, hb);
    k_gemm<2><<<dim3(16, 24, 8), 256, 0, stream>>>(hb, w2t, b2, counts, offs, ltok, lw, yb);
    k_combine<<<8192, 256, 0, stream>>>(yb, tslot, out);
}